// Round 6
// baseline (432.226 us; speedup 1.0000x reference)
//
#include <hip/hip_runtime.h>

#define TAGS 64
#define MAXT 512
#define NEG  -10000.0f
#define CH   8   // feat-staging chunk: steps per LDS buffer

// One wave (64 lanes) per batch. lane = "next" tag.
// Round-6: the fv broadcast goes through the REGISTER FILE, not LDS.
// Each lane keeps its own fv value in register nf; v_readlane_b32 broadcasts
// all 64 values as SGPRs each step (wave lockstep => all readlanes see the
// previous step's nf). This deletes the fv LDS round-trip whose ~860
// cyc/step latency the compiler refused to hide in rounds 3/5 (VGPR count
// 132 showed it never software-pipelined the deferred index scan).
// Step is now issue-bound: ~320 VALU instrs, no memory on the chain.
__global__ __launch_bounds__(64, 1) void crf_viterbi(
    const float* __restrict__ feats,   // [B, T, K]
    const float* __restrict__ weights, // [K, K] (weights[next][prev])
    const int*   __restrict__ lens,    // [B]
    float*       __restrict__ out,     // [B] scores ++ [B*T] paths (as f32)
    int B, int T)
{
    const int b    = blockIdx.x;
    const int lane = threadIdx.x;              // next tag
    const int len  = lens[b];                  // 1..T

    __shared__ float fbuf[2][CH * TAGS];       // 2 x 2 KB feat staging
    __shared__ unsigned char  bptr[MAXT * TAGS];
    __shared__ unsigned short path[MAXT];
    // ~37 KB LDS -> 4 blocks/CU

    // W row for this lane -> 64 VGPRs, reused every step
    float w[TAGS];
    #pragma unroll
    for (int i = 0; i < 16; ++i) {
        const float4 v = *reinterpret_cast<const float4*>(weights + lane * TAGS + i * 4);
        w[4*i+0] = v.x; w[4*i+1] = v.y; w[4*i+2] = v.z; w[4*i+3] = v.w;
    }
    const float wEnd = weights[1 * TAGS + lane];  // transition into END

    const float* fb  = feats + (size_t)b * T * TAGS;
    const int    lim = len * TAGS - 4;            // clamp for tail loads

    float nf = (lane == 0) ? 0.0f : NEG;          // fv[lane]; START = 0

#define F3(a, b, c) fmaxf(fmaxf((a), (b)), (c))
#define M3(a, b, c) min(min((a), (b)), (c))

    auto step = [&](int cbuf, int i, int t) {
        const float feat = fbuf[cbuf][i * TAGS + lane];  // off-chain LDS read

        // broadcast previous fv via register file; c[p] = fv[p] + W[lane][p]
        float c[TAGS];
        #pragma unroll
        for (int p = 0; p < TAGS; ++p) {
            const float fp = __int_as_float(
                __builtin_amdgcn_readlane(__float_as_int(nf), p));
            c[p] = fp + w[p];
        }

        // value-only max: 3-ary tree (v_max3_f32), 32 ops, depth 4
        float v1[22];
        #pragma unroll
        for (int k = 0; k < 21; ++k) v1[k] = F3(c[3*k], c[3*k+1], c[3*k+2]);
        v1[21] = c[63];
        float v2[8];
        #pragma unroll
        for (int k = 0; k < 7; ++k) v2[k] = F3(v1[3*k], v1[3*k+1], v1[3*k+2]);
        v2[7] = v1[21];
        const float v30 = F3(v2[0], v2[1], v2[2]);
        const float v31 = F3(v2[3], v2[4], v2[5]);
        const float v32 = fmaxf(v2[6], v2[7]);
        const float m   = F3(v30, v31, v32);

        nf = m + feat;                 // emission after max; next step's input

        // index: first p with c[p]==m (numpy first-occurrence, exact f32 ==).
        // (c[p] != m) ? 64 : p  ->  v_cmp_neq + v_cndmask(p_inline, v64)
        unsigned e[TAGS];
        #pragma unroll
        for (int p = 0; p < TAGS; ++p)
            e[p] = (c[p] != m) ? 64u : (unsigned)p;
        unsigned u1[22];
        #pragma unroll
        for (int k = 0; k < 21; ++k) u1[k] = M3(e[3*k], e[3*k+1], e[3*k+2]);
        u1[21] = e[63];
        unsigned u2[8];
        #pragma unroll
        for (int k = 0; k < 7; ++k) u2[k] = M3(u1[3*k], u1[3*k+1], u1[3*k+2]);
        u2[7] = u1[21];
        const unsigned u30 = M3(u2[0], u2[1], u2[2]);
        const unsigned u31 = M3(u2[3], u2[4], u2[5]);
        const unsigned u32 = min(u2[6], u2[7]);
        const unsigned idx = M3(u30, u31, u32);

        bptr[t * TAGS + lane] = (unsigned char)idx;
    };

    // prologue: stage chunk 0 -> fbuf[0]; issue chunk-1 loads
    {
        int o0 = 4 * lane;        if (o0 > lim) o0 = lim;
        int o1 = 256 + 4 * lane;  if (o1 > lim) o1 = lim;
        *reinterpret_cast<float4*>(&fbuf[0][4 * lane])       = *reinterpret_cast<const float4*>(fb + o0);
        *reinterpret_cast<float4*>(&fbuf[0][256 + 4 * lane]) = *reinterpret_cast<const float4*>(fb + o1);
    }
    float4 n0, n1;
    {
        int o0 = CH * TAGS + 4 * lane;        if (o0 > lim) o0 = lim;
        int o1 = CH * TAGS + 256 + 4 * lane;  if (o1 > lim) o1 = lim;
        n0 = *reinterpret_cast<const float4*>(fb + o0);
        n1 = *reinterpret_cast<const float4*>(fb + o1);
    }

    int cb = 0;
    const int nfull = len / CH;
    for (int c = 0; c < nfull; ++c) {
        #pragma unroll
        for (int i = 0; i < CH; ++i) step(cb, i, c * CH + i);
        // stage chunk c+1 (loads landed ~8 steps ago), issue chunk c+2
        *reinterpret_cast<float4*>(&fbuf[cb ^ 1][4 * lane])       = n0;
        *reinterpret_cast<float4*>(&fbuf[cb ^ 1][256 + 4 * lane]) = n1;
        {
            int o0 = (c + 2) * CH * TAGS + 4 * lane;        if (o0 > lim) o0 = lim;
            int o1 = (c + 2) * CH * TAGS + 256 + 4 * lane;  if (o1 > lim) o1 = lim;
            n0 = *reinterpret_cast<const float4*>(fb + o0);
            n1 = *reinterpret_cast<const float4*>(fb + o1);
        }
        cb ^= 1;
    }
    const int rem = len - nfull * CH;             // 0..7 remainder steps
    for (int i = 0; i < rem; ++i) step(cb, i, nfull * CH + i);

    // terminal = fv + W[END][prev]; first-max argmax via shuffle butterfly
    float tv = nf + wEnd;
    int   ti = lane;
    #pragma unroll
    for (int off = 32; off >= 1; off >>= 1) {
        const float ov = __shfl_xor(tv, off);
        const int   oi = __shfl_xor(ti, off);
        if (ov > tv || (ov == tv && oi < ti)) { tv = ov; ti = oi; }
    }
    if (lane == 0) out[b] = tv;
    const int bestlast = ti;                      // uniform across lanes

    // padding region: path[t] = bestlast for t in [len-1, T)
    for (int t = lane; t < T; t += 64)
        if (t >= len - 1) path[t] = (unsigned short)bestlast;
    __builtin_amdgcn_wave_barrier();

    // serial chase (lane 0, LDS-resident backpointers)
    if (lane == 0) {
        int tag = bestlast;
        for (int t = len - 1; t >= 1; --t) {
            tag = bptr[t * TAGS + tag];
            path[t - 1] = (unsigned short)tag;
        }
    }
    __builtin_amdgcn_wave_barrier();

    // coalesced path writeback (tags as float32)
    float* pout = out + B + (size_t)b * T;
    for (int t = lane; t < T; t += 64)
        pout[t] = (float)path[t];
}

extern "C" void kernel_launch(void* const* d_in, const int* in_sizes, int n_in,
                              void* d_out, int out_size, void* d_ws, size_t ws_size,
                              hipStream_t stream) {
    const float* feats   = (const float*)d_in[0];
    const float* weights = (const float*)d_in[1];
    const int*   lens    = (const int*)d_in[2];
    float*       out     = (float*)d_out;

    const int B = in_sizes[2];
    const int T = in_sizes[0] / (B * TAGS);

    crf_viterbi<<<dim3(B), dim3(64), 0, stream>>>(feats, weights, lens, out, B, T);
}

// Round 7
// 425.046 us; speedup vs baseline: 1.0169x; 1.0169x over previous
//
#include <hip/hip_runtime.h>

#define TAGS 64
#define MAXT 512
#define NEG  -10000.0f
#define CH   8   // feat-staging chunk: steps per LDS buffer

// One wave (64 lanes) per batch. lane = "next" tag. Round-5 body (best so
// far), ONE change: LDS padded to ~56 KB to force 2 blocks/CU instead of 4.
// Rationale: rounds 3/5/6 had 253/414/321 instrs/step and three different
// broadcast mechanisms yet identical 1330-1380 cyc/step => per-step time is
// set by a CU-SHARED resource under 4-way single-wave-block contention
// (LDS pipe / I-fetch), not by the wave's own instruction stream. Halving
// co-residency halves the contention on the critical len=512 block; the
// scheduler refills freed slots so total throughput is preserved.
__global__ __launch_bounds__(64, 1) void crf_viterbi(
    const float* __restrict__ feats,   // [B, T, K]
    const float* __restrict__ weights, // [K, K] (weights[next][prev])
    const int*   __restrict__ lens,    // [B]
    float*       __restrict__ out,     // [B] scores ++ [B*T] paths (as f32)
    int B, int T)
{
    const int b    = blockIdx.x;
    const int lane = threadIdx.x;              // next tag
    const int len  = lens[b];                  // 1..T

    __shared__ float fv[TAGS];
    __shared__ float fbuf[2][CH * TAGS];       // 2 x 2 KB feat staging
    __shared__ unsigned char  bptr[MAXT * TAGS];
    __shared__ unsigned short path[MAXT];
    __shared__ float lds_pad[4608];            // occupancy throttle: ->2 blocks/CU
    // ~56.3 KB LDS -> floor(160K / 56.3K) = 2 blocks/CU

    // keep the pad alive without ever touching it at runtime
    if (b == 0x7fffffff) lds_pad[lane] = (float)len, fv[lane] = lds_pad[lane ^ 1];

    // W row for this lane (as float4 quads)
    float4 w4[16];
    #pragma unroll
    for (int i = 0; i < 16; ++i)
        w4[i] = *reinterpret_cast<const float4*>(weights + lane * TAGS + i * 4);
    const float wEnd = weights[1 * TAGS + lane];  // transition into END

    fv[lane] = (lane == 0) ? 0.0f : NEG;          // START = 0

    const float* fb  = feats + (size_t)b * T * TAGS;
    const int    lim = len * TAGS - 4;            // clamp for tail loads

    float nf = NEG;                               // this lane's running fv

#define F3(a, b, c) fmaxf(fmaxf((a), (b)), (c))
#define M3(a, b, c) min(min((a), (b)), (c))

    auto step = [&](int cbuf, int i, int t) {
        const float feat = fbuf[cbuf][i * TAGS + lane];  // early, off-chain
        // gather fv quads (16x ds_read_b128)
        float4 fq[16];
        #pragma unroll
        for (int g = 0; g < 16; ++g)
            fq[g] = *reinterpret_cast<const float4*>(&fv[g * 4]);
        // c = fv + w
        float4 c4[16];
        #pragma unroll
        for (int g = 0; g < 16; ++g) {
            c4[g].x = fq[g].x + w4[g].x;
            c4[g].y = fq[g].y + w4[g].y;
            c4[g].z = fq[g].z + w4[g].z;
            c4[g].w = fq[g].w + w4[g].w;
        }
        const float* c = reinterpret_cast<const float*>(c4);

        // value-only max: 3-ary tree (v_max3_f32), depth 4
        float v1[22];
        #pragma unroll
        for (int k = 0; k < 21; ++k) v1[k] = F3(c[3*k], c[3*k+1], c[3*k+2]);
        v1[21] = c[63];
        float v2[8];
        #pragma unroll
        for (int k = 0; k < 7; ++k) v2[k] = F3(v1[3*k], v1[3*k+1], v1[3*k+2]);
        v2[7] = v1[21];
        const float v30 = F3(v2[0], v2[1], v2[2]);
        const float v31 = F3(v2[3], v2[4], v2[5]);
        const float v32 = fmaxf(v2[6], v2[7]);
        const float m   = F3(v30, v31, v32);

        nf = m + feat;                 // emission added after max
        fv[lane] = nf;                 // unblocks step t+1

        // deferred index: first p with c[p]==m (numpy first-occurrence,
        // exact f32 ==; no NaNs in this data)
        unsigned e[64];
        #pragma unroll
        for (int p = 0; p < 64; ++p) e[p] = (c[p] == m) ? (unsigned)p : 64u;
        unsigned u1[22];
        #pragma unroll
        for (int k = 0; k < 21; ++k) u1[k] = M3(e[3*k], e[3*k+1], e[3*k+2]);
        u1[21] = e[63];
        unsigned u2[8];
        #pragma unroll
        for (int k = 0; k < 7; ++k) u2[k] = M3(u1[3*k], u1[3*k+1], u1[3*k+2]);
        u2[7] = u1[21];
        const unsigned u30 = M3(u2[0], u2[1], u2[2]);
        const unsigned u31 = M3(u2[3], u2[4], u2[5]);
        const unsigned u32 = min(u2[6], u2[7]);
        const unsigned idx = M3(u30, u31, u32);

        bptr[t * TAGS + lane] = (unsigned char)idx;
    };

    // prologue: stage chunk 0 -> fbuf[0]; issue chunk-1 loads
    {
        int o0 = 4 * lane;        if (o0 > lim) o0 = lim;
        int o1 = 256 + 4 * lane;  if (o1 > lim) o1 = lim;
        *reinterpret_cast<float4*>(&fbuf[0][4 * lane])       = *reinterpret_cast<const float4*>(fb + o0);
        *reinterpret_cast<float4*>(&fbuf[0][256 + 4 * lane]) = *reinterpret_cast<const float4*>(fb + o1);
    }
    float4 n0, n1;
    {
        int o0 = CH * TAGS + 4 * lane;        if (o0 > lim) o0 = lim;
        int o1 = CH * TAGS + 256 + 4 * lane;  if (o1 > lim) o1 = lim;
        n0 = *reinterpret_cast<const float4*>(fb + o0);
        n1 = *reinterpret_cast<const float4*>(fb + o1);
    }

    int cb = 0;
    const int nfull = len / CH;
    for (int c = 0; c < nfull; ++c) {
        #pragma unroll
        for (int i = 0; i < CH; ++i) step(cb, i, c * CH + i);
        // stage chunk c+1 (loads landed ~8 steps ago), issue chunk c+2
        *reinterpret_cast<float4*>(&fbuf[cb ^ 1][4 * lane])       = n0;
        *reinterpret_cast<float4*>(&fbuf[cb ^ 1][256 + 4 * lane]) = n1;
        {
            int o0 = (c + 2) * CH * TAGS + 4 * lane;        if (o0 > lim) o0 = lim;
            int o1 = (c + 2) * CH * TAGS + 256 + 4 * lane;  if (o1 > lim) o1 = lim;
            n0 = *reinterpret_cast<const float4*>(fb + o0);
            n1 = *reinterpret_cast<const float4*>(fb + o1);
        }
        cb ^= 1;
    }
    const int rem = len - nfull * CH;             // 0..7 remainder steps
    for (int i = 0; i < rem; ++i) step(cb, i, nfull * CH + i);

    // terminal = fv + W[END][prev]; first-max argmax via shuffle butterfly
    float tv = nf + wEnd;
    int   ti = lane;
    #pragma unroll
    for (int off = 32; off >= 1; off >>= 1) {
        const float ov = __shfl_xor(tv, off);
        const int   oi = __shfl_xor(ti, off);
        if (ov > tv || (ov == tv && oi < ti)) { tv = ov; ti = oi; }
    }
    if (lane == 0) out[b] = tv;
    const int bestlast = ti;                      // uniform across lanes

    // padding region: path[t] = bestlast for t in [len-1, T)
    for (int t = lane; t < T; t += 64)
        if (t >= len - 1) path[t] = (unsigned short)bestlast;
    __builtin_amdgcn_wave_barrier();

    // serial chase (lane 0, LDS-resident backpointers)
    if (lane == 0) {
        int tag = bestlast;
        for (int t = len - 1; t >= 1; --t) {
            tag = bptr[t * TAGS + tag];
            path[t - 1] = (unsigned short)tag;
        }
    }
    __builtin_amdgcn_wave_barrier();

    // coalesced path writeback (tags as float32)
    float* pout = out + B + (size_t)b * T;
    for (int t = lane; t < T; t += 64)
        pout[t] = (float)path[t];
}

extern "C" void kernel_launch(void* const* d_in, const int* in_sizes, int n_in,
                              void* d_out, int out_size, void* d_ws, size_t ws_size,
                              hipStream_t stream) {
    const float* feats   = (const float*)d_in[0];
    const float* weights = (const float*)d_in[1];
    const int*   lens    = (const int*)d_in[2];
    float*       out     = (float*)d_out;

    const int B = in_sizes[2];
    const int T = in_sizes[0] / (B * TAGS);

    crf_viterbi<<<dim3(B), dim3(64), 0, stream>>>(feats, weights, lens, out, B, T);
}